// Round 4
// baseline (3888.239 us; speedup 1.0000x reference)
//
#include <hip/hip_runtime.h>
#include <stdint.h>

// B=32, T=128, DIN=DOUT=1024. Input dtypes detected at runtime (bf16 vs fp32).
typedef unsigned short u16;
typedef unsigned long long u64;
typedef __attribute__((ext_vector_type(8))) short short8;   // 8 x bf16 MFMA operand
typedef __attribute__((ext_vector_type(4))) float f32x4;    // MFMA accumulator

// ---- workspace layout (bytes) ----
// Tagged-message buffers: u64 word = [tag:16 | v2:16 | v1:16 | v0:16] (3 bf16).
// hm / rhm: [parity 2][row 32][oct 128][3] u64 = 196608 B each. memset 0 gives
// tag=0 values=0 everywhere: tag 0 == h0 epoch, zeros == h0 values (perfect seed).
#define FLG_OFF    0                          // 13 dtype flags
#define HM_OFF     4096                       // h tagged msgs: 196608 B
#define RHM_OFF    (HM_OFF + 196608)          // r*h tagged msgs: 196608 B
#define ZERO_BYTES (RHM_OFF + 196608)
#define BS_OFF     ZERO_BYTES                 // bias sums fp32: 3*1024*4
#define XB_OFF     (1<<20)                    // x bf16: 8 MB
#define WB_OFF     (9<<20)                    // 6 weight mats bf16: 12 MB
#define WS_FULL    (21u<<20)
#define PAR_STRIDE 12288                      // 32*128*3 u64 per parity

__device__ __forceinline__ float bf2f(u16 v) {
    unsigned u = ((unsigned)v) << 16;
    return __builtin_bit_cast(float, u);
}
__device__ __forceinline__ u16 f2bf(float f) {
    unsigned u = __builtin_bit_cast(unsigned, f);
    unsigned r = 0x7fffu + ((u >> 16) & 1u);   // RNE
    return (u16)((u + r) >> 16);
}
__device__ __forceinline__ float sigm(float x) { return 1.0f / (1.0f + __expf(-x)); }

__device__ __forceinline__ short8 cvt8f(const float* f) {
    short8 r;
#pragma unroll
    for (int j = 0; j < 8; j++) r[j] = (short)f2bf(f[j]);
    return r;
}
__device__ __forceinline__ short8 cvt8any(const void* src, long ei, unsigned isbf) {
    if (isbf) return *(const short8*)((const u16*)src + ei);
    return cvt8f((const float*)src + ei);
}

// sc1 (L2-bypassing, L3-coherent) 64-bit message ops. A 64b aligned access is
// atomic: tag and data arrive in one snapshot -> no fences/flags needed.
__device__ __forceinline__ u64 ld64(const u64* p) {
    return __hip_atomic_load(p, __ATOMIC_RELAXED, __HIP_MEMORY_SCOPE_AGENT);
}
__device__ __forceinline__ void st64(u64* p, u64 v) {
    __hip_atomic_store(p, v, __ATOMIC_RELAXED, __HIP_MEMORY_SCOPE_AGENT);
}

// Poll NC chunks (3 u64 each, stride 12 u64 between chunks) until every word's
// tag == want. First round: bulk load (1 L3 trip if producer already done).
// Then: cheap canary spin (word 0 of each chunk) before full re-verify, to
// avoid hammering L3 with 24-word reloads while waiting.
template<int NC>
__device__ __forceinline__ void poll_chunks(u64* m, const u64* base, u64 want) {
#pragma unroll
    for (int i = 0; i < NC; i++) {
#pragma unroll
        for (int j = 0; j < 3; j++) m[i * 3 + j] = ld64(base + i * 12 + j);
    }
    bool ok = true;
#pragma unroll
    for (int q = 0; q < NC * 3; q++) ok &= ((m[q] >> 48) == want);
    while (!ok) {
        bool c;
        do {
            c = true;
            __builtin_amdgcn_s_sleep(2);
#pragma unroll
            for (int i = 0; i < NC; i++) {
                u64 w = ld64(base + i * 12);
                c &= ((w >> 48) == want);
                m[i * 3] = w;
            }
        } while (!c);
#pragma unroll
        for (int i = 0; i < NC; i++) {
            m[i * 3 + 1] = ld64(base + i * 12 + 1);
            m[i * 3 + 2] = ld64(base + i * 12 + 2);
        }
        ok = true;
#pragma unroll
        for (int q = 0; q < NC * 3; q++) ok &= ((m[q] >> 48) == want);
    }
}

// Assemble one MFMA operand (8 bf16 = one K-octet) from 3 tagged words.
__device__ __forceinline__ short8 asm8(const u64* m) {
    short8 a;
    a[0] = (short)(u16)m[0]; a[1] = (short)(u16)(m[0] >> 16); a[2] = (short)(u16)(m[0] >> 32);
    a[3] = (short)(u16)m[1]; a[4] = (short)(u16)(m[1] >> 16); a[5] = (short)(u16)(m[1] >> 32);
    a[6] = (short)(u16)m[2]; a[7] = (short)(u16)(m[2] >> 16);
    return a;
}

// Publish a 16x16 bf16 tile (rows R..R+15, cols 16*ct..+15) from tT as
// 96 tagged u64 (16 rows x 2 octets x 3 words). Fire-and-forget sc1 stores.
__device__ __forceinline__ void publish_tile(u64* dst, int R, int ct, unsigned tag,
                                             const u16 (*tT)[20], int lane) {
#pragma unroll
    for (int pass = 0; pass < 2; pass++) {
        int g = lane + pass * 64;
        if (g < 96) {
            int lr = g / 6, w = g - lr * 6, oc = w / 3, j = w - oc * 3;
            int cb = oc * 8 + j * 3;
            u64 v0 = tT[lr][cb];
            u64 v1 = tT[lr][cb + 1];
            u64 v2 = (j == 2) ? 0ull : (u64)tT[lr][cb + 2];
            u64 word = v0 | (v1 << 16) | (v2 << 32) | ((u64)tag << 48);
            st64(dst + ((long)(R + lr) * 128 + 2 * ct + oc) * 3 + j, word);
        }
    }
}

struct Ptrs { const void* p[13]; };

// dtype detector: bf16 u16s have exponent in [100,140] (or zero) ~100% for
// N(0,s) data; fp32 read as u16 passes ~58%.
__global__ __launch_bounds__(256) void detect_k(Ptrs ps, unsigned* flags) {
    const u16* a = (const u16*)ps.p[blockIdx.x];
    __shared__ int tot;
    if (threadIdx.x == 0) tot = 0;
    __syncthreads();
    int cnt = 0;
    for (int i = threadIdx.x; i < 1024; i += 256) {
        unsigned u = a[i];
        unsigned e = (u >> 7) & 0xFF;
        cnt += (e == 0 || (e >= 100 && e <= 140)) ? 1 : 0;
    }
    atomicAdd(&tot, cnt);
    __syncthreads();
    if (threadIdx.x == 0) flags[blockIdx.x] = (tot >= 920) ? 1u : 0u;
}

struct SPtrs { const void* x; const void* W[6]; const void* b[6]; };
// W order: Wz,Uz,Wr,Ur,Wh,Uh (flags 1,3,5,7,9,11); b pairs (bz,cz),(br,cr),(bh,ch).

__global__ __launch_bounds__(256) void stage_k(SPtrs ps, const unsigned* __restrict__ flags,
                                               u16* __restrict__ xb, u16* __restrict__ wb,
                                               float* __restrict__ bs, int do_x) {
    int blk = blockIdx.x, tid = threadIdx.x;
    int xblocks = do_x ? 2048 : 0;
    if (blk < xblocks) {                         // x: 4M elems
        long ei = ((long)blk * 256 + tid) * 8;
        *(short8*)(xb + ei) = cvt8any(ps.x, ei, flags[0]);
    } else if (blk < xblocks + 6 * 512) {        // weights: 1M elems each
        int r = (blk - xblocks) >> 9;
        const int fidx[6] = {1, 3, 5, 7, 9, 11};
        long ei = ((long)((blk - xblocks) & 511) * 256 + tid) * 8;
        *(short8*)(wb + (long)r * 1048576 + ei) = cvt8any(ps.W[r], ei, flags[fidx[r]]);
    } else {                                     // bias sums: bs[0]=z, [1]=r, [2]=h
        const int fb[3] = {2, 6, 10}, fc[3] = {4, 8, 12};
        for (int g = 0; g < 3; g++)
            for (int i = tid; i < 1024; i += 256) {
                float b = flags[fb[g]] ? bf2f(((const u16*)ps.b[2 * g])[i])
                                       : ((const float*)ps.b[2 * g])[i];
                float c = flags[fc[g]] ? bf2f(((const u16*)ps.b[2 * g + 1])[i])
                                       : ((const float*)ps.b[2 * g + 1])[i];
                bs[g * 1024 + i] = b + c;
            }
    }
}

// ---- persistent GRU: 128 blocks x 1024 thr (16 waves), dataflow sync ----
// Block (ct=blk>>1, rt=blk&1) owns rows R=[16rt,+16) (batch), cols C=[16ct,+16).
// NO grid barriers, NO flags. h and r*h travel as epoch-tagged u64 messages
// ([tag|3xbf16], parity double-buffered). Consumers poll exact tag match;
// the tag+data atomicity of a 64b word makes the protocol fence-free.
//
// WAR safety (why tag t+2 can't overwrite a slot still being read at tag t):
// writer reaches tag t+2 only after completing step t+1 phase B <- needs rh
// tag t+2 from ALL same-rt producers <- each passed its phase A of t+1 <-
// program order: each completed (successfully polled) its phase A reads of
// tag t. Readers of a slot are exactly that producer set -> safe, and
// exact-match polling can never miss an epoch -> no deadlock.
//
// h tags: h input to step t has tag t (h0 = memset zeros, tag 0), parity t&1.
// rh tags: published during step t with tag t+1, parity t&1.
__global__ __launch_bounds__(1024, 4) void gru_rec(
    const void* __restrict__ xbase, int xmode,   // 1: xbase bf16-staged; 0: raw x
    const u16* __restrict__ wb, const float* __restrict__ bs,
    u64* __restrict__ hm, u64* __restrict__ rhm,
    const unsigned* __restrict__ flags,
    void* __restrict__ out)
{
    const int tid  = threadIdx.x;
    const int lane = tid & 63, wave = tid >> 6;      // wave 0..15
    const int quad = lane >> 4, ln = lane & 15;
    const int blk  = blockIdx.x;

    const unsigned xisbf = xmode ? 1u : flags[0];
    const unsigned outbf = flags[0];

    const int ct = blk >> 1, rt = blk & 1;
    const int R = rt * 16, C0 = ct * 16;

    // Phase A role: g = wave>>2 (0:hUr 1:xWr 2:hUz 3:xWz), kq = wave&3.
    const int gA  = wave >> 2, kqA = wave & 3;
    const int kb0 = kqA * 256;
    const int wmapA[4] = {3, 2, 1, 0};               // -> Ur, Wr, Uz, Wz
    const u16* BwA = wb + (long)wmapA[gA] * 1048576 + (C0 + ln) * 1024 + kb0 + quad * 8;
    const bool hA  = (gA == 0) || (gA == 2);
    // tagged-msg base (u64): [row=R+ln][oct=kqA*32+quad], chunk i at +12*i
    const long hAoff = ((long)(R + ln) * 128 + kqA * 32 + quad) * 3;
    const long xAo = ((long)(R + ln) * 128) * 1024 + kb0 + quad * 8; // + t*1024

    // Phase B role: gB = wave>>3 (0:rh@Uh 1:x@Wh), ke = wave&7.
    const int gB  = wave >> 3, keB = wave & 7;
    const int kb1 = keB * 128;
    const u16* BwB = wb + (long)(gB ? 4 : 5) * 1048576 + (C0 + ln) * 1024 + kb1 + quad * 8;
    const long rhoff = ((long)(R + ln) * 128 + keB * 16 + quad) * 3;
    const long xBo = ((long)(R + ln) * 128) * 1024 + kb1 + quad * 8; // + t*1024

    const float bias_z = bs[C0 + ln];
    const float bias_r = bs[1024 + C0 + ln];
    const float bias_h = bs[2048 + C0 + ln];

    __shared__ float sA[16][4][64];    // phase-A partials
    __shared__ float sB[16][4][64];    // phase-B partials (separate: waves run ahead)
    __shared__ float zt[4][64];        // z tile
    __shared__ float ht[4][64];        // h fp32 tile (block-private)
    __shared__ u16   tT[16][20];       // transpose staging for tile publish

    if (wave == 0)
#pragma unroll
        for (int r = 0; r < 4; r++) ht[r][lane] = 0.f;
    __syncthreads();

    for (int t = 0; t < 128; t++) {
        { // ---- phase A chains: 8 MFMAs ----
            f32x4 acc = (f32x4){0.f, 0.f, 0.f, 0.f};
            if (hA) {
                u64 m[24];
                poll_chunks<8>(m, hm + (t & 1) * PAR_STRIDE + hAoff, (u64)t);
#pragma unroll
                for (int i = 0; i < 8; i++)
                    acc = __builtin_amdgcn_mfma_f32_16x16x32_bf16(
                        asm8(m + i * 3), *(const short8*)(BwA + i * 32), acc, 0, 0, 0);
            } else {
                const long xo = xAo + (long)t * 1024;
#pragma unroll
                for (int i = 0; i < 8; i++)
                    acc = __builtin_amdgcn_mfma_f32_16x16x32_bf16(
                        cvt8any(xbase, xo + i * 32, xisbf),
                        *(const short8*)(BwA + i * 32), acc, 0, 0, 0);
            }
#pragma unroll
            for (int r = 0; r < 4; r++) sA[wave][r][lane] = acc[r];
        }
        __syncthreads();                 // sync1: sA complete
        if (wave == 0) {        // r -> r*h, transpose via LDS, publish tagged
#pragma unroll
            for (int r = 0; r < 4; r++) {
                float s = bias_r;
#pragma unroll
                for (int w = 0; w < 8; w++) s += sA[w][r][lane];
                float rv = sigm(s);
                tT[quad * 4 + r][ln] = f2bf(rv * ht[r][lane]);
            }
            publish_tile(rhm + (t & 1) * PAR_STRIDE, R, ct, (unsigned)(t + 1), tT, lane);
        } else if (wave == 1) { // z -> LDS
#pragma unroll
            for (int r = 0; r < 4; r++) {
                float s = bias_z;
#pragma unroll
                for (int w = 8; w < 16; w++) s += sA[w][r][lane];
                zt[r][lane] = sigm(s);
            }
        }
        { // ---- phase B chains: 4 MFMAs ----
            f32x4 acc = (f32x4){0.f, 0.f, 0.f, 0.f};
            if (gB == 0) {
                u64 m[12];
                poll_chunks<4>(m, rhm + (t & 1) * PAR_STRIDE + rhoff, (u64)(t + 1));
#pragma unroll
                for (int i = 0; i < 4; i++)
                    acc = __builtin_amdgcn_mfma_f32_16x16x32_bf16(
                        asm8(m + i * 3), *(const short8*)(BwB + i * 32), acc, 0, 0, 0);
            } else {
                const long xo = xBo + (long)t * 1024;
#pragma unroll
                for (int i = 0; i < 4; i++)
                    acc = __builtin_amdgcn_mfma_f32_16x16x32_bf16(
                        cvt8any(xbase, xo + i * 32, xisbf),
                        *(const short8*)(BwB + i * 32), acc, 0, 0, 0);
            }
#pragma unroll
            for (int r = 0; r < 4; r++) sB[wave][r][lane] = acc[r];
        }
        __syncthreads();                 // sync2: sB complete
        if (wave == 0) {        // combine: h' = (1-z)h + z*sigm(.), publish h
#pragma unroll
            for (int r = 0; r < 4; r++) {
                float s = bias_h;
#pragma unroll
                for (int w = 0; w < 16; w++) s += sB[w][r][lane];
                float hh = sigm(s);
                float z  = zt[r][lane];
                float hv = ht[r][lane];
                float hn = (1.0f - z) * hv + z * hh;
                ht[r][lane] = hn;
                u16 hb = f2bf(hn);
                int row = quad * 4 + r;
                tT[row][ln] = hb;
                long oi = ((long)(t * 32) + R + row) * 1024 + C0 + ln;  // ys (T,B,D)
                if (outbf) ((u16*)out)[oi] = hb;
                else       ((float*)out)[oi] = hn;
            }
            publish_tile(hm + ((t + 1) & 1) * PAR_STRIDE, R, ct, (unsigned)(t + 1), tT, lane);
        }
    }
}

extern "C" void kernel_launch(void* const* d_in, const int* in_sizes, int n_in,
                              void* d_out, int out_size, void* d_ws, size_t ws_size,
                              hipStream_t stream)
{
    char* ws = (char*)d_ws;
    hipMemsetAsync(d_ws, 0, ZERO_BYTES, stream);   // dtype flags + hm + rhm

    unsigned* flags = (unsigned*)(ws + FLG_OFF);
    u64*      hm    = (u64*)(ws + HM_OFF);
    u64*      rhm   = (u64*)(ws + RHM_OFF);
    float*    bs    = (float*)(ws + BS_OFF);
    u16*      xb    = (u16*)(ws + XB_OFF);

    Ptrs dp;
    for (int i = 0; i < 13; i++) dp.p[i] = d_in[i];
    detect_k<<<13, 256, 0, stream>>>(dp, flags);

    SPtrs sp;
    sp.x = d_in[0];
    sp.W[0] = d_in[1];  sp.W[1] = d_in[3];   // Wz, Uz
    sp.W[2] = d_in[5];  sp.W[3] = d_in[7];   // Wr, Ur
    sp.W[4] = d_in[9];  sp.W[5] = d_in[11];  // Wh, Uh
    sp.b[0] = d_in[2];  sp.b[1] = d_in[4];   // bz, cz
    sp.b[2] = d_in[6];  sp.b[3] = d_in[8];   // br, cr
    sp.b[4] = d_in[10]; sp.b[5] = d_in[12];  // bh, ch

    if (ws_size >= WS_FULL) {
        u16* wbuf = (u16*)(ws + WB_OFF);
        stage_k<<<2048 + 6 * 512 + 1, 256, 0, stream>>>(sp, flags, xb, wbuf, bs, 1);
        gru_rec<<<128, 1024, 0, stream>>>(xb, 1, wbuf, bs, hm, rhm, flags, d_out);
    } else {
        u16* wbuf = (u16*)(ws + XB_OFF);     // no x staging; weights at 1 MB
        stage_k<<<6 * 512 + 1, 256, 0, stream>>>(sp, flags, xb, wbuf, bs, 0);
        gru_rec<<<128, 1024, 0, stream>>>(d_in[0], 0, wbuf, bs, hm, rhm, flags, d_out);
    }
}

// Round 5
// 1632.409 us; speedup vs baseline: 2.3819x; 2.3819x over previous
//
#include <hip/hip_runtime.h>
#include <stdint.h>

// B=32, T=128, DIN=DOUT=1024. Input dtypes detected at runtime (bf16 vs fp32).
typedef unsigned short u16;
typedef unsigned long long u64;
typedef __attribute__((ext_vector_type(8))) short short8;   // 8 x bf16 MFMA operand
typedef __attribute__((ext_vector_type(4))) float f32x4;    // MFMA accumulator

// ---- workspace layout (bytes) ----
// Anti-contention layout: barrier flags strided 1KB (channel spread) with 4
// intra-page replicas 256B apart (line fan-out 128 -> 32 pollers); h and r*h
// tile buffers replicated 4x (64KB each) so each data line serves ~4x fewer
// readers and the buffers span 512KB of channels instead of 128KB.
#define CNT_OFF    0                          // barrier flags: 128 x 1KB (zeroed)
#define FLG_OFF    131072                     // 13 dtype flags
#define BS_OFF     135168                     // bias sums fp32: 3*1024*4
#define H64_OFF    147456                     // h bf16 u64[4 rep][32][256]: 256 KB (zeroed)
#define ZERO_BYTES (H64_OFF + 262144)
#define RH64_OFF   ZERO_BYTES                 // r*h u64[4 rep][32][256]: 256 KB (wbr)
#define XB_OFF     (1<<20)                    // x bf16: 8 MB
#define WB_OFF     (9<<20)                    // 6 weight mats bf16: 12 MB
#define WS_FULL    (21u<<20)
#define REP_STRIDE 8192                       // u64 per replica (64 KB)

__device__ __forceinline__ float bf2f(u16 v) {
    unsigned u = ((unsigned)v) << 16;
    return __builtin_bit_cast(float, u);
}
__device__ __forceinline__ u16 f2bf(float f) {
    unsigned u = __builtin_bit_cast(unsigned, f);
    unsigned r = 0x7fffu + ((u >> 16) & 1u);   // RNE
    return (u16)((u + r) >> 16);
}
__device__ __forceinline__ float sigm(float x) { return 1.0f / (1.0f + __expf(-x)); }

__device__ __forceinline__ short8 cvt8f(const float* f) {
    short8 r;
#pragma unroll
    for (int j = 0; j < 8; j++) r[j] = (short)f2bf(f[j]);
    return r;
}
__device__ __forceinline__ short8 cvt8any(const void* src, long ei, unsigned isbf) {
    if (isbf) return *(const short8*)((const u16*)src + ei);
    return cvt8f((const float*)src + ei);
}

union Q2 { u64 q[2]; short8 s; };
// Coherent (L2-bypassing, sc1) 16-byte fragment load as two relaxed agent atomics.
__device__ __forceinline__ short8 ld_coh8(const u64* p) {
    Q2 u;
    u.q[0] = __hip_atomic_load(p,     __ATOMIC_RELAXED, __HIP_MEMORY_SCOPE_AGENT);
    u.q[1] = __hip_atomic_load(p + 1, __ATOMIC_RELAXED, __HIP_MEMORY_SCOPE_AGENT);
    return u.s;
}
__device__ __forceinline__ unsigned ld_flag(const unsigned* p) {
    return __hip_atomic_load(p, __ATOMIC_RELAXED, __HIP_MEMORY_SCOPE_AGENT);
}
__device__ __forceinline__ void st_flag(unsigned* p, unsigned v) {
    __hip_atomic_store(p, v, __ATOMIC_RELAXED, __HIP_MEMORY_SCOPE_AGENT);
}
__device__ __forceinline__ void st64(u64* p, u64 v) {
    __hip_atomic_store(p, v, __ATOMIC_RELAXED, __HIP_MEMORY_SCOPE_AGENT);
}

// ---- leaderless all-to-all grid barrier (round-1 protocol, de-contended) ----
// Each block stores a MONOTONE epoch to 4 replica lines of its own 1KB-strided
// flag page (no contention, no RMW); threads 0..NB-1 each poll one block's
// flag, reading replica (blk&3) -> per-line fan-out 32 instead of 128, and
// polls spread over 128 channels-worth of addresses instead of 8KB.
// Ordering: data moves via sc1 atomics (coherent at L3); __syncthreads drains
// vmcnt so all data stores (incl. all replicas) are visible BEFORE the flag
// stores issue; consumer loads are also sc1 so they cannot hit stale L2.
// Flags zeroed once by memset; epochs 1..255 strictly increase per launch.
__device__ __forceinline__ void gbar(unsigned* flgs, unsigned e, unsigned nb) {
    __syncthreads();                 // drains vmcnt: all sc1 data stores at L3
    const unsigned tid = threadIdx.x;
    if (tid < 4)
        st_flag(flgs + blockIdx.x * 256 + tid * 64, e);   // 4 replicas, 256B apart
    if (tid < nb) {
        const unsigned* fp = flgs + tid * 256 + (blockIdx.x & 3) * 64;
        while (ld_flag(fp) < e)
            __builtin_amdgcn_s_sleep(1);
    }
    __syncthreads();
}

struct Ptrs { const void* p[13]; };

// dtype detector: bf16 u16s have exponent in [100,140] (or zero) ~100% for
// N(0,s) data; fp32 read as u16 passes ~58%.
__global__ __launch_bounds__(256) void detect_k(Ptrs ps, unsigned* flags) {
    const u16* a = (const u16*)ps.p[blockIdx.x];
    __shared__ int tot;
    if (threadIdx.x == 0) tot = 0;
    __syncthreads();
    int cnt = 0;
    for (int i = threadIdx.x; i < 1024; i += 256) {
        unsigned u = a[i];
        unsigned e = (u >> 7) & 0xFF;
        cnt += (e == 0 || (e >= 100 && e <= 140)) ? 1 : 0;
    }
    atomicAdd(&tot, cnt);
    __syncthreads();
    if (threadIdx.x == 0) flags[blockIdx.x] = (tot >= 920) ? 1u : 0u;
}

struct SPtrs { const void* x; const void* W[6]; const void* b[6]; };
// W order: Wz,Uz,Wr,Ur,Wh,Uh (flags 1,3,5,7,9,11); b pairs (bz,cz),(br,cr),(bh,ch).

__global__ __launch_bounds__(256) void stage_k(SPtrs ps, const unsigned* __restrict__ flags,
                                               u16* __restrict__ xb, u16* __restrict__ wb,
                                               float* __restrict__ bs, int do_x) {
    int blk = blockIdx.x, tid = threadIdx.x;
    int xblocks = do_x ? 2048 : 0;
    if (blk < xblocks) {                         // x: 4M elems
        long ei = ((long)blk * 256 + tid) * 8;
        *(short8*)(xb + ei) = cvt8any(ps.x, ei, flags[0]);
    } else if (blk < xblocks + 6 * 512) {        // weights: 1M elems each
        int r = (blk - xblocks) >> 9;
        const int fidx[6] = {1, 3, 5, 7, 9, 11};
        long ei = ((long)((blk - xblocks) & 511) * 256 + tid) * 8;
        *(short8*)(wb + (long)r * 1048576 + ei) = cvt8any(ps.W[r], ei, flags[fidx[r]]);
    } else {                                     // bias sums: bs[0]=z, [1]=r, [2]=h
        const int fb[3] = {2, 6, 10}, fc[3] = {4, 8, 12};
        for (int g = 0; g < 3; g++)
            for (int i = tid; i < 1024; i += 256) {
                float b = flags[fb[g]] ? bf2f(((const u16*)ps.b[2 * g])[i])
                                       : ((const float*)ps.b[2 * g])[i];
                float c = flags[fc[g]] ? bf2f(((const u16*)ps.b[2 * g + 1])[i])
                                       : ((const float*)ps.b[2 * g + 1])[i];
                bs[g * 1024 + i] = b + c;
            }
    }
}

// ---- persistent GRU: 128 blocks x 1024 thr (16 waves), K-split chains ----
// Block (ct=blk>>1, rt=blk&1) owns rows R=[16rt,+16) (batch), cols C=[16ct,+16).
// h and r*h live as u64[4 replicas][32][256] (4 bf16 per u64), accessed ONLY
// via sc1 atomics (L3 coherence point). Producers write all 4 replicas
// (fire-and-forget, one shared vmcnt drain); consumers read replica (blk&3)
// -> each L3 data line serves ~32 readers instead of 128.
// Protocol is the proven round-1 design: 2 full leaderless barriers per step.
__global__ __launch_bounds__(1024, 4) void gru_rec(
    const void* __restrict__ xbase, int xmode,   // 1: xbase bf16-staged; 0: raw x
    const u16* __restrict__ wb, const float* __restrict__ bs,
    u64* __restrict__ h64, u64* __restrict__ rh64,
    const unsigned* __restrict__ flags,
    unsigned* __restrict__ flgs,
    void* __restrict__ out)
{
    const int tid  = threadIdx.x;
    const int lane = tid & 63, wave = tid >> 6;      // wave 0..15
    const int quad = lane >> 4, ln = lane & 15;
    const int blk  = blockIdx.x;
    const unsigned NB = gridDim.x;
    const int rep  = blk & 3;                        // data replica this block reads

    const unsigned xisbf = xmode ? 1u : flags[0];
    const unsigned outbf = flags[0];

    const int ct = blk >> 1, rt = blk & 1;
    const int R = rt * 16, C0 = ct * 16;

    // Phase A role: g = wave>>2 (0:hUr 1:xWr 2:hUz 3:xWz), kq = wave&3.
    const int gA  = wave >> 2, kqA = wave & 3;
    const int kb0 = kqA * 256;
    const int wmapA[4] = {3, 2, 1, 0};               // -> Ur, Wr, Uz, Wz
    const u16* BwA = wb + (long)wmapA[gA] * 1048576 + (C0 + ln) * 1024 + kb0 + quad * 8;
    const bool hA  = (gA == 0) || (gA == 2);
    const u64* hAq = h64 + rep * REP_STRIDE + (R + ln) * 256 + (kb0 >> 2) + quad * 2; // +i*8
    const long xAo = ((long)(R + ln) * 128) * 1024 + kb0 + quad * 8; // + t*1024

    // Phase B role: gB = wave>>3 (0:rh@Uh 1:x@Wh), ke = wave&7.
    const int gB  = wave >> 3, keB = wave & 7;
    const int kb1 = keB * 128;
    const u16* BwB = wb + (long)(gB ? 4 : 5) * 1048576 + (C0 + ln) * 1024 + kb1 + quad * 8;
    const u64* rhq = rh64 + rep * REP_STRIDE + (R + ln) * 256 + (kb1 >> 2) + quad * 2; // +i*8
    const long xBo = ((long)(R + ln) * 128) * 1024 + kb1 + quad * 8; // + t*1024

    const float bias_z = bs[C0 + ln];
    const float bias_r = bs[1024 + C0 + ln];
    const float bias_h = bs[2048 + C0 + ln];

    __shared__ float sA[16][4][64];    // per-wave partials, conflict-free layout
    __shared__ float zt[4][64];        // z tile
    __shared__ float ht[4][64];        // h fp32 tile (block-private)
    __shared__ u16   tT[16][20];       // transpose staging for u64 packing

    if (wave == 0)
#pragma unroll
        for (int r = 0; r < 4; r++) ht[r][lane] = 0.f;
    __syncthreads();

    const int prow = lane >> 2, pseg = lane & 3;     // packer geometry (wave 0)

    for (int t = 0; t < 128; t++) {
        { // ---- phase A chains: 8 MFMAs ----
            f32x4 acc = (f32x4){0.f, 0.f, 0.f, 0.f};
            const long xo = xAo + (long)t * 1024;
#pragma unroll
            for (int i = 0; i < 8; i++) {
                short8 a = hA ? ld_coh8(hAq + i * 8)
                              : cvt8any(xbase, xo + i * 32, xisbf);
                acc = __builtin_amdgcn_mfma_f32_16x16x32_bf16(
                    a, *(const short8*)(BwA + i * 32), acc, 0, 0, 0);
            }
#pragma unroll
            for (int r = 0; r < 4; r++) sA[wave][r][lane] = acc[r];
        }
        __syncthreads();
        if (wave == 0) {        // r -> r*h, transpose via LDS, publish 4 replicas
#pragma unroll
            for (int r = 0; r < 4; r++) {
                float s = bias_r;
#pragma unroll
                for (int w = 0; w < 8; w++) s += sA[w][r][lane];
                float rv = sigm(s);
                tT[quad * 4 + r][ln] = f2bf(rv * ht[r][lane]);
            }
            u64 v = (u64)tT[prow][pseg * 4] | ((u64)tT[prow][pseg * 4 + 1] << 16)
                  | ((u64)tT[prow][pseg * 4 + 2] << 32) | ((u64)tT[prow][pseg * 4 + 3] << 48);
            u64* dst = &rh64[(R + prow) * 256 + ct * 4 + pseg];
#pragma unroll
            for (int rp = 0; rp < 4; rp++) st64(dst + rp * REP_STRIDE, v);
        } else if (wave == 1) { // z -> LDS
#pragma unroll
            for (int r = 0; r < 4; r++) {
                float s = bias_z;
#pragma unroll
                for (int w = 8; w < 16; w++) s += sA[w][r][lane];
                zt[r][lane] = sigm(s);
            }
        }
        gbar(flgs, 2 * t + 1, NB);
        { // ---- phase B chains: 4 MFMAs ----
            f32x4 acc = (f32x4){0.f, 0.f, 0.f, 0.f};
            const long xo = xBo + (long)t * 1024;
#pragma unroll
            for (int i = 0; i < 4; i++) {
                short8 a = (gB == 0) ? ld_coh8(rhq + i * 8)
                                     : cvt8any(xbase, xo + i * 32, xisbf);
                acc = __builtin_amdgcn_mfma_f32_16x16x32_bf16(
                    a, *(const short8*)(BwB + i * 32), acc, 0, 0, 0);
            }
#pragma unroll
            for (int r = 0; r < 4; r++) sA[wave][r][lane] = acc[r];
        }
        __syncthreads();
        if (wave == 0) {        // combine: h' = (1-z)h + z*sigm(.), publish h x4
#pragma unroll
            for (int r = 0; r < 4; r++) {
                float s = bias_h;
#pragma unroll
                for (int w = 0; w < 16; w++) s += sA[w][r][lane];
                float hh = sigm(s);
                float z  = zt[r][lane];
                float hv = ht[r][lane];
                float hn = (1.0f - z) * hv + z * hh;
                ht[r][lane] = hn;
                u16 hb = f2bf(hn);
                int row = quad * 4 + r;
                tT[row][ln] = hb;
                long oi = ((long)(t * 32) + R + row) * 1024 + C0 + ln;  // ys (T,B,D)
                if (outbf) ((u16*)out)[oi] = hb;
                else       ((float*)out)[oi] = hn;
            }
            u64 v = (u64)tT[prow][pseg * 4] | ((u64)tT[prow][pseg * 4 + 1] << 16)
                  | ((u64)tT[prow][pseg * 4 + 2] << 32) | ((u64)tT[prow][pseg * 4 + 3] << 48);
            u64* dst = &h64[(R + prow) * 256 + ct * 4 + pseg];
#pragma unroll
            for (int rp = 0; rp < 4; rp++) st64(dst + rp * REP_STRIDE, v);
        }
        if (t < 127) gbar(flgs, 2 * t + 2, NB);
    }
}

extern "C" void kernel_launch(void* const* d_in, const int* in_sizes, int n_in,
                              void* d_out, int out_size, void* d_ws, size_t ws_size,
                              hipStream_t stream)
{
    char* ws = (char*)d_ws;
    hipMemsetAsync(d_ws, 0, ZERO_BYTES, stream);   // barrier flags + dtypes + h64 reps

    unsigned* flgs  = (unsigned*)(ws + CNT_OFF);
    unsigned* flags = (unsigned*)(ws + FLG_OFF);
    float*    bs    = (float*)(ws + BS_OFF);
    u64*      h64   = (u64*)(ws + H64_OFF);
    u64*      rh64  = (u64*)(ws + RH64_OFF);
    u16*      xb    = (u16*)(ws + XB_OFF);

    Ptrs dp;
    for (int i = 0; i < 13; i++) dp.p[i] = d_in[i];
    detect_k<<<13, 256, 0, stream>>>(dp, flags);

    SPtrs sp;
    sp.x = d_in[0];
    sp.W[0] = d_in[1];  sp.W[1] = d_in[3];   // Wz, Uz
    sp.W[2] = d_in[5];  sp.W[3] = d_in[7];   // Wr, Ur
    sp.W[4] = d_in[9];  sp.W[5] = d_in[11];  // Wh, Uh
    sp.b[0] = d_in[2];  sp.b[1] = d_in[4];   // bz, cz
    sp.b[2] = d_in[6];  sp.b[3] = d_in[8];   // br, cr
    sp.b[4] = d_in[10]; sp.b[5] = d_in[12];  // bh, ch

    if (ws_size >= WS_FULL) {
        u16* wbuf = (u16*)(ws + WB_OFF);
        stage_k<<<2048 + 6 * 512 + 1, 256, 0, stream>>>(sp, flags, xb, wbuf, bs, 1);
        gru_rec<<<128, 1024, 0, stream>>>(xb, 1, wbuf, bs, h64, rh64, flags, flgs, d_out);
    } else {
        u16* wbuf = (u16*)(ws + XB_OFF);     // no x staging; weights at 1 MB
        stage_k<<<6 * 512 + 1, 256, 0, stream>>>(sp, flags, xb, wbuf, bs, 0);
        gru_rec<<<128, 1024, 0, stream>>>(d_in[0], 0, wbuf, bs, h64, rh64, flags, flgs, d_out);
    }
}

// Round 7
// 1430.210 us; speedup vs baseline: 2.7186x; 1.1414x over previous
//
#include <hip/hip_runtime.h>
#include <stdint.h>

// B=32, T=128, DIN=DOUT=1024. Input dtypes detected at runtime (bf16 vs fp32).
typedef unsigned short u16;
typedef unsigned long long u64;
typedef __attribute__((ext_vector_type(8))) short short8;   // 8 x bf16 MFMA operand
typedef __attribute__((ext_vector_type(4))) float f32x4;    // MFMA accumulator

// ---- workspace layout (bytes) ----
// Anti-contention layout (R5, kept): barrier flags strided 1KB with 4 replicas
// 256B apart; h and r*h tile buffers replicated 4x.
#define CNT_OFF    0                          // barrier flags: 128 x 1KB (zeroed)
#define FLG_OFF    131072                     // 13 dtype flags
#define BS_OFF     135168                     // bias sums fp32: 3*1024*4
#define H64_OFF    147456                     // h bf16 u64[4 rep][32][256]: 256 KB (zeroed)
#define ZERO_BYTES (H64_OFF + 262144)
#define RH64_OFF   ZERO_BYTES                 // r*h u64[4 rep][32][256]: 256 KB (wbr)
#define XB_OFF     (1<<20)                    // x bf16: 8 MB
#define WB_OFF     (9<<20)                    // 6 weight mats bf16: 12 MB
#define WS_FULL    (21u<<20)
#define REP_STRIDE 8192                       // u64 per replica (64 KB)

__device__ __forceinline__ float bf2f(u16 v) {
    unsigned u = ((unsigned)v) << 16;
    return __builtin_bit_cast(float, u);
}
__device__ __forceinline__ u16 f2bf(float f) {
    unsigned u = __builtin_bit_cast(unsigned, f);
    unsigned r = 0x7fffu + ((u >> 16) & 1u);   // RNE
    return (u16)((u + r) >> 16);
}
__device__ __forceinline__ float sigm(float x) { return 1.0f / (1.0f + __expf(-x)); }

__device__ __forceinline__ short8 cvt8f(const float* f) {
    short8 r;
#pragma unroll
    for (int j = 0; j < 8; j++) r[j] = (short)f2bf(f[j]);
    return r;
}
__device__ __forceinline__ short8 cvt8any(const void* src, long ei, unsigned isbf) {
    if (isbf) return *(const short8*)((const u16*)src + ei);
    return cvt8f((const float*)src + ei);
}

union Q2 { u64 q[2]; short8 s; };
// Coherent (L2-bypassing, sc1) 16-byte fragment load as two relaxed agent atomics.
__device__ __forceinline__ short8 ld_coh8(const u64* p) {
    Q2 u;
    u.q[0] = __hip_atomic_load(p,     __ATOMIC_RELAXED, __HIP_MEMORY_SCOPE_AGENT);
    u.q[1] = __hip_atomic_load(p + 1, __ATOMIC_RELAXED, __HIP_MEMORY_SCOPE_AGENT);
    return u.s;
}
__device__ __forceinline__ u64 ld64(const u64* p) {
    return __hip_atomic_load(p, __ATOMIC_RELAXED, __HIP_MEMORY_SCOPE_AGENT);
}
__device__ __forceinline__ unsigned ld_flag(const unsigned* p) {
    return __hip_atomic_load(p, __ATOMIC_RELAXED, __HIP_MEMORY_SCOPE_AGENT);
}
__device__ __forceinline__ void st_flag(unsigned* p, unsigned v) {
    __hip_atomic_store(p, v, __ATOMIC_RELAXED, __HIP_MEMORY_SCOPE_AGENT);
}
__device__ __forceinline__ void st64(u64* p, u64 v) {
    __hip_atomic_store(p, v, __ATOMIC_RELAXED, __HIP_MEMORY_SCOPE_AGENT);
}

// ---- leaderless all-to-all grid barrier (R5, kept) ----
// Each block stores a MONOTONE epoch to 4 replica lines of its own 1KB-strided
// flag page; threads 0..NB-1 each poll one block's flag, reading replica
// (blk&3). Ordering: data moves via sc1 atomics (coherent at L3);
// __syncthreads drains vmcnt so all data stores are visible BEFORE the flag
// stores issue; consumer loads are also sc1 so they cannot hit stale L2.
__device__ __forceinline__ void gbar(unsigned* flgs, unsigned e, unsigned nb) {
    __syncthreads();                 // drains vmcnt: all sc1 data stores at L3
    const unsigned tid = threadIdx.x;
    if (tid < 4)
        st_flag(flgs + blockIdx.x * 256 + tid * 64, e);   // 4 replicas, 256B apart
    if (tid < nb) {
        const unsigned* fp = flgs + tid * 256 + (blockIdx.x & 3) * 64;
        while (ld_flag(fp) < e)
            __builtin_amdgcn_s_sleep(1);
    }
    __syncthreads();
}

struct Ptrs { const void* p[13]; };

// dtype detector: bf16 u16s have exponent in [100,140] (or zero) ~100% for
// N(0,s) data; fp32 read as u16 passes ~58%.
__global__ __launch_bounds__(256) void detect_k(Ptrs ps, unsigned* flags) {
    const u16* a = (const u16*)ps.p[blockIdx.x];
    __shared__ int tot;
    if (threadIdx.x == 0) tot = 0;
    __syncthreads();
    int cnt = 0;
    for (int i = threadIdx.x; i < 1024; i += 256) {
        unsigned u = a[i];
        unsigned e = (u >> 7) & 0xFF;
        cnt += (e == 0 || (e >= 100 && e <= 140)) ? 1 : 0;
    }
    atomicAdd(&tot, cnt);
    __syncthreads();
    if (threadIdx.x == 0) flags[blockIdx.x] = (tot >= 920) ? 1u : 0u;
}

struct SPtrs { const void* x; const void* W[6]; const void* b[6]; };
// W order: Wz,Uz,Wr,Ur,Wh,Uh (flags 1,3,5,7,9,11); b pairs (bz,cz),(br,cr),(bh,ch).

__global__ __launch_bounds__(256) void stage_k(SPtrs ps, const unsigned* __restrict__ flags,
                                               u16* __restrict__ xb, u16* __restrict__ wb,
                                               float* __restrict__ bs, int do_x) {
    int blk = blockIdx.x, tid = threadIdx.x;
    int xblocks = do_x ? 2048 : 0;
    if (blk < xblocks) {                         // x: 4M elems
        long ei = ((long)blk * 256 + tid) * 8;
        *(short8*)(xb + ei) = cvt8any(ps.x, ei, flags[0]);
    } else if (blk < xblocks + 6 * 512) {        // weights: 1M elems each
        int r = (blk - xblocks) >> 9;
        const int fidx[6] = {1, 3, 5, 7, 9, 11};
        long ei = ((long)((blk - xblocks) & 511) * 256 + tid) * 8;
        *(short8*)(wb + (long)r * 1048576 + ei) = cvt8any(ps.W[r], ei, flags[fidx[r]]);
    } else {                                     // bias sums: bs[0]=z, [1]=r, [2]=h
        const int fb[3] = {2, 6, 10}, fc[3] = {4, 8, 12};
        for (int g = 0; g < 3; g++)
            for (int i = tid; i < 1024; i += 256) {
                float b = flags[fb[g]] ? bf2f(((const u16*)ps.b[2 * g])[i])
                                       : ((const float*)ps.b[2 * g])[i];
                float c = flags[fc[g]] ? bf2f(((const u16*)ps.b[2 * g + 1])[i])
                                       : ((const float*)ps.b[2 * g + 1])[i];
                bs[g * 1024 + i] = b + c;
            }
    }
}

// ---- persistent GRU: 128 blocks x 1024 thr (16 waves), K-split chains ----
// Block (ct=blk>>1, rt=blk&1) owns rows R=[16rt,+16) (batch), cols C=[16ct,+16).
// h and r*h live as u64[4 replicas][32][256] (4 bf16 per u64), accessed ONLY
// via sc1 atomics (L3 coherence point).
//
// R6/R7 change (sc1-THROUGHPUT hypothesis): the hUz and hUr wave groups used
// to each pull the same 16 h-rows via sc1 (64 KB/block/step). Now all 16 waves
// cooperatively stage the 32 KB of h rows into LDS once per step, and both
// groups read operands from LDS -> h sc1 volume halves (8 -> 4 MB/step
// grid-wide; total sc1 12 -> 8 MB/step). Ordering/WAR inherited verbatim:
// staging reads sit exactly where the old phase-A reads sat, guarded by the
// same trailing grid barrier.
__global__ __launch_bounds__(1024, 4) void gru_rec(
    const void* __restrict__ xbase, int xmode,   // 1: xbase bf16-staged; 0: raw x
    const u16* __restrict__ wb, const float* __restrict__ bs,
    u64* __restrict__ h64, u64* __restrict__ rh64,
    const unsigned* __restrict__ flags,
    unsigned* __restrict__ flgs,
    void* __restrict__ out)
{
    const int tid  = threadIdx.x;
    const int lane = tid & 63, wave = tid >> 6;      // wave 0..15
    const int quad = lane >> 4, ln = lane & 15;
    const int blk  = blockIdx.x;
    const unsigned NB = gridDim.x;
    const int rep  = blk & 3;                        // data replica this block reads

    const unsigned xisbf = xmode ? 1u : flags[0];
    const unsigned outbf = flags[0];

    const int ct = blk >> 1, rt = blk & 1;
    const int R = rt * 16, C0 = ct * 16;

    // Phase A role: g = wave>>2 (0:hUr 1:xWr 2:hUz 3:xWz), kq = wave&3.
    const int gA  = wave >> 2, kqA = wave & 3;
    const int kb0 = kqA * 256;
    const int wmapA[4] = {3, 2, 1, 0};               // -> Ur, Wr, Uz, Wz
    const u16* BwA = wb + (long)wmapA[gA] * 1048576 + (C0 + ln) * 1024 + kb0 + quad * 8;
    const bool hA  = (gA == 0) || (gA == 2);
    const int hsc  = (kb0 >> 2) + quad * 2;          // hs u64 col base; iter i: +i*8
    const long xAo = ((long)(R + ln) * 128) * 1024 + kb0 + quad * 8; // + t*1024

    // Phase B role: gB = wave>>3 (0:rh@Uh 1:x@Wh), ke = wave&7.
    const int gB  = wave >> 3, keB = wave & 7;
    const int kb1 = keB * 128;
    const u16* BwB = wb + (long)(gB ? 4 : 5) * 1048576 + (C0 + ln) * 1024 + kb1 + quad * 8;
    const u64* rhq = rh64 + rep * REP_STRIDE + (R + ln) * 256 + (kb1 >> 2) + quad * 2; // +i*8
    const long xBo = ((long)(R + ln) * 128) * 1024 + kb1 + quad * 8; // + t*1024

    const float bias_z = bs[C0 + ln];
    const float bias_r = bs[1024 + C0 + ln];
    const float bias_h = bs[2048 + C0 + ln];

    __shared__ float sA[16][4][64];    // per-wave partials, conflict-free layout
    __shared__ float zt[4][64];        // z tile
    __shared__ float ht[4][64];        // h fp32 tile (block-private)
    __shared__ u16   tT[16][20];       // transpose staging for u64 packing
    __shared__ u64   hs[16][258];      // staged h rows: 16 x 256 u64 (+2 pad: 16B
                                       // align kept, row stride 2064B -> 2-way banks)

    if (wave == 0)
#pragma unroll
        for (int r = 0; r < 4; r++) ht[r][lane] = 0.f;
    __syncthreads();

    const int prow = lane >> 2, pseg = lane & 3;     // packer geometry (wave 0)

    // staging source: wave w loads row R+w, lane l covers cols l, l+64, l+128, l+192
    const u64* hsrc = h64 + rep * REP_STRIDE + (R + wave) * 256 + lane;

    for (int t = 0; t < 128; t++) {
        { // ---- stage h rows into LDS (one sc1 read per word per block) ----
#pragma unroll
            for (int c = 0; c < 4; c++)
                hs[wave][lane + 64 * c] = ld64(hsrc + 64 * c);
        }
        __syncthreads();
        { // ---- phase A chains: 8 MFMAs ----
            f32x4 acc = (f32x4){0.f, 0.f, 0.f, 0.f};
            const long xo = xAo + (long)t * 1024;
#pragma unroll
            for (int i = 0; i < 8; i++) {
                short8 a = hA ? *(const short8*)&hs[ln][hsc + i * 8]
                              : cvt8any(xbase, xo + i * 32, xisbf);
                acc = __builtin_amdgcn_mfma_f32_16x16x32_bf16(
                    a, *(const short8*)(BwA + i * 32), acc, 0, 0, 0);
            }
#pragma unroll
            for (int r = 0; r < 4; r++) sA[wave][r][lane] = acc[r];
        }
        __syncthreads();
        if (wave == 0) {        // r -> r*h, transpose via LDS, publish 4 replicas
#pragma unroll
            for (int r = 0; r < 4; r++) {
                float s = bias_r;
#pragma unroll
                for (int w = 0; w < 8; w++) s += sA[w][r][lane];
                float rv = sigm(s);
                tT[quad * 4 + r][ln] = f2bf(rv * ht[r][lane]);
            }
            u64 v = (u64)tT[prow][pseg * 4] | ((u64)tT[prow][pseg * 4 + 1] << 16)
                  | ((u64)tT[prow][pseg * 4 + 2] << 32) | ((u64)tT[prow][pseg * 4 + 3] << 48);
            u64* dst = &rh64[(R + prow) * 256 + ct * 4 + pseg];
#pragma unroll
            for (int rp = 0; rp < 4; rp++) st64(dst + rp * REP_STRIDE, v);
        } else if (wave == 1) { // z -> LDS
#pragma unroll
            for (int r = 0; r < 4; r++) {
                float s = bias_z;
#pragma unroll
                for (int w = 8; w < 16; w++) s += sA[w][r][lane];
                zt[r][lane] = sigm(s);
            }
        }
        gbar(flgs, 2 * t + 1, NB);
        { // ---- phase B chains: 4 MFMAs ----
            f32x4 acc = (f32x4){0.f, 0.f, 0.f, 0.f};
            const long xo = xBo + (long)t * 1024;
#pragma unroll
            for (int i = 0; i < 4; i++) {
                short8 a = (gB == 0) ? ld_coh8(rhq + i * 8)
                                     : cvt8any(xbase, xo + i * 32, xisbf);
                acc = __builtin_amdgcn_mfma_f32_16x16x32_bf16(
                    a, *(const short8*)(BwB + i * 32), acc, 0, 0, 0);
            }
#pragma unroll
            for (int r = 0; r < 4; r++) sA[wave][r][lane] = acc[r];
        }
        __syncthreads();
        if (wave == 0) {        // combine: h' = (1-z)h + z*sigm(.), publish h x4
#pragma unroll
            for (int r = 0; r < 4; r++) {
                float s = bias_h;
#pragma unroll
                for (int w = 0; w < 16; w++) s += sA[w][r][lane];
                float hh = sigm(s);
                float z  = zt[r][lane];
                float hv = ht[r][lane];
                float hn = (1.0f - z) * hv + z * hh;
                ht[r][lane] = hn;
                u16 hb = f2bf(hn);
                int row = quad * 4 + r;
                tT[row][ln] = hb;
                long oi = ((long)(t * 32) + R + row) * 1024 + C0 + ln;  // ys (T,B,D)
                if (outbf) ((u16*)out)[oi] = hb;
                else       ((float*)out)[oi] = hn;
            }
            u64 v = (u64)tT[prow][pseg * 4] | ((u64)tT[prow][pseg * 4 + 1] << 16)
                  | ((u64)tT[prow][pseg * 4 + 2] << 32) | ((u64)tT[prow][pseg * 4 + 3] << 48);
            u64* dst = &h64[(R + prow) * 256 + ct * 4 + pseg];
#pragma unroll
            for (int rp = 0; rp < 4; rp++) st64(dst + rp * REP_STRIDE, v);
        }
        if (t < 127) gbar(flgs, 2 * t + 2, NB);
    }
}

extern "C" void kernel_launch(void* const* d_in, const int* in_sizes, int n_in,
                              void* d_out, int out_size, void* d_ws, size_t ws_size,
                              hipStream_t stream)
{
    char* ws = (char*)d_ws;
    hipMemsetAsync(d_ws, 0, ZERO_BYTES, stream);   // barrier flags + dtypes + h64 reps

    unsigned* flgs  = (unsigned*)(ws + CNT_OFF);
    unsigned* flags = (unsigned*)(ws + FLG_OFF);
    float*    bs    = (float*)(ws + BS_OFF);
    u64*      h64   = (u64*)(ws + H64_OFF);
    u64*      rh64  = (u64*)(ws + RH64_OFF);
    u16*      xb    = (u16*)(ws + XB_OFF);

    Ptrs dp;
    for (int i = 0; i < 13; i++) dp.p[i] = d_in[i];
    detect_k<<<13, 256, 0, stream>>>(dp, flags);

    SPtrs sp;
    sp.x = d_in[0];
    sp.W[0] = d_in[1];  sp.W[1] = d_in[3];   // Wz, Uz
    sp.W[2] = d_in[5];  sp.W[3] = d_in[7];   // Wr, Ur
    sp.W[4] = d_in[9];  sp.W[5] = d_in[11];  // Wh, Uh
    sp.b[0] = d_in[2];  sp.b[1] = d_in[4];   // bz, cz
    sp.b[2] = d_in[6];  sp.b[3] = d_in[8];   // br, cr
    sp.b[4] = d_in[10]; sp.b[5] = d_in[12];  // bh, ch

    if (ws_size >= WS_FULL) {
        u16* wbuf = (u16*)(ws + WB_OFF);
        stage_k<<<2048 + 6 * 512 + 1, 256, 0, stream>>>(sp, flags, xb, wbuf, bs, 1);
        gru_rec<<<128, 1024, 0, stream>>>(xb, 1, wbuf, bs, h64, rh64, flags, flgs, d_out);
    } else {
        u16* wbuf = (u16*)(ws + XB_OFF);     // no x staging; weights at 1 MB
        stage_k<<<6 * 512 + 1, 256, 0, stream>>>(sp, flags, xb, wbuf, bs, 0);
        gru_rec<<<128, 1024, 0, stream>>>(d_in[0], 0, wbuf, bs, h64, rh64, flags, flgs, d_out);
    }
}